// Round 2
// baseline (688.085 us; speedup 1.0000x reference)
//
#include <hip/hip_runtime.h>

typedef unsigned short ushort_t;
typedef unsigned int u32;
typedef float f32x4 __attribute__((ext_vector_type(4)));
typedef short s16x8 __attribute__((ext_vector_type(8)));

#define BROWS 4096
#define DIMK  1024
#define RANKK 256
#define TROWS 16
#define GPAD  (RANKK + 8)

#define DTF 0.01f
#define THETAF 1.35120719195965763f
#define C1F    0.675603595979828816f   // THETA/2
#define C2F   (-0.175603595979828816f) // (1-THETA)/2
#define D1F    1.35120719195965763f    // THETA
#define D2F   (-1.70241438391931526f)  // 1-2*THETA

#define CHUNK_US 16384   // ushorts per 32KB chunk
#define NCHUNK   32      // 16 Ut chunks + 16 Wt chunks per accel pass

__device__ __forceinline__ ushort_t f2bf(float f) {
    unsigned u = __builtin_bit_cast(unsigned, f);
    return (ushort_t)((u + 0x7FFFu + ((u >> 16) & 1u)) >> 16);
}

__device__ __forceinline__ void gload_lds16(const ushort_t* g, ushort_t* l) {
    __builtin_amdgcn_global_load_lds(
        (const __attribute__((address_space(1))) u32*)g,
        (__attribute__((address_space(3))) u32*)l, 16, 0, 0);
}

// ---------------------------------------------------------------------------
// Pack U [1024 k][256 r] f32 -> UtC: 16 chunks of [256 n][64 k] bf16, k-slot
// XOR-swizzled within each 128B row: slot_phys = (kj>>3) ^ (n&7).
// ---------------------------------------------------------------------------
__global__ void fr_pack_u(const float* __restrict__ U, ushort_t* __restrict__ UtC) {
    const int idx = blockIdx.x * 256 + threadIdx.x;   // 0 .. 262143
    const int k = idx >> 8, n = idx & 255;
    const int c = k >> 6, kj = k & 63;
    const int dest = (c * 256 + n) * 64 + ((((kj >> 3) ^ (n & 7)) << 3) | (kj & 7));
    UtC[dest] = f2bf(U[idx]);
}

// ---------------------------------------------------------------------------
// Pack W [256 r][1024 d] f32 -> WtC: 16 chunks cc = (kslice*2 + n_half):
// chunk = [512 n_local][32 k] bf16 (32B rows -> naturally bank-staggered).
// ---------------------------------------------------------------------------
__global__ void fr_pack_w(const float* __restrict__ W, ushort_t* __restrict__ WtC) {
    const int idx = blockIdx.x * 256 + threadIdx.x;   // 0 .. 262143
    const int kr = idx >> 10, n = idx & 1023;
    const int t = kr >> 5, kl = kr & 31;
    const int half = n >> 9, nl = n & 511;
    const int dest = (t * 2 + half) * CHUNK_US + nl * 32 + kl;
    WtC[dest] = f2bf(W[idx]);
}

// ---------------------------------------------------------------------------
// Fused Forest-Ruth integrator, async-staged B operands.
// Block = 16 rows, 512 threads (8 waves). Per accel: 32 chunk-steps, each
// {lgkmcnt(0); s_barrier; stage(s+2) via global_load_lds; vmcnt(8); s_barrier;
//  MFMA on chunk s}. Ring of 3 x 32KB LDS buffers, B never drained to vmcnt 0.
// ---------------------------------------------------------------------------
__global__ __launch_bounds__(512, 2) void fr_kernel(
    const float* __restrict__ x_in, const float* __restrict__ v_in,
    const float* __restrict__ f_in, const ushort_t* __restrict__ BC,
    const int* __restrict__ steps_p, float* __restrict__ out) {
    __shared__ ushort_t ring[3][CHUNK_US];   // 96 KB
    __shared__ ushort_t vb[TROWS * DIMK];    // 32 KB, XOR-swizzled rows
    __shared__ ushort_t gb[TROWS * GPAD];    // 8.25 KB, padded rows

    const int tid  = threadIdx.x;
    const int lane = tid & 63;
    const int wave = tid >> 6;          // 0..7
    const int m16  = lane & 15;
    const int g4   = lane >> 4;         // 0..3
    const int row0 = blockIdx.x * TROWS;
    const int n_acc = 3 * steps_p[0];

    // fragment ownership: i = nt*4 + r;  m = g4*4 + r;  n = wave*128 + nt*16 + m16
    float vreg[32], xreg[32], freg[32];
#pragma unroll
    for (int nt = 0; nt < 8; ++nt) {
#pragma unroll
        for (int r = 0; r < 4; ++r) {
            const int m = g4 * 4 + r;
            const int n = wave * 128 + nt * 16 + m16;
            const size_t gi = (size_t)(row0 + m) * DIMK + n;
            const float v0 = v_in[gi];
            vreg[nt * 4 + r] = v0;
            xreg[nt * 4 + r] = x_in[gi] + (C1F * DTF) * v0;  // first x-substep folded
            freg[nt * 4 + r] = f_in[gi];
            vb[m * DIMK + (n ^ ((m & 7) << 3))] = f2bf(v0);
        }
    }
    // prologue staging of chunks 0,1
#pragma unroll
    for (int i = 0; i < 4; ++i) {
        const int q = i * 512 + tid;
        gload_lds16(BC + q * 8, &ring[0][0] + q * 8);
    }
#pragma unroll
    for (int i = 0; i < 4; ++i) {
        const int q = i * 512 + tid;
        gload_lds16(BC + CHUNK_US + q * 8, &ring[1][0] + q * 8);
    }
    __syncthreads();   // full drain once: vb + chunks 0,1 ready

    int S = 0;
    f32x4 acc[8];
    const int half_w = wave >> 2, wl = wave & 3;
    const int n1a = wave * 32 + m16, n1b = n1a + 16;

    for (int j = 0; j < n_acc; ++j) {
        // ================= phase 1: h = v @ U, chunks 0..15 =================
        f32x4 h0 = {0.f, 0.f, 0.f, 0.f}, h1 = {0.f, 0.f, 0.f, 0.f};
        for (int s = 0; s < 16; ++s) {
            asm volatile("s_waitcnt lgkmcnt(0)" ::: "memory");
            __builtin_amdgcn_s_barrier();                 // B1: prev compute done
            asm volatile("" ::: "memory");
            {
                const ushort_t* src = BC + ((S + 2) & 31) * CHUNK_US;
                ushort_t* dst = &ring[(S + 2) % 3][0];
#pragma unroll
                for (int i = 0; i < 4; ++i) {
                    const int q = i * 512 + tid;
                    gload_lds16(src + q * 8, dst + q * 8);
                }
            }
            asm volatile("s_waitcnt vmcnt(8)" ::: "memory");
            __builtin_amdgcn_s_barrier();                 // B2: chunk s landed
            __builtin_amdgcn_sched_barrier(0);
            asm volatile("" ::: "memory");
            const ushort_t* buf = &ring[S % 3][0];
#pragma unroll
            for (int kk = 0; kk < 2; ++kk) {
                const int kel = s * 64 + kk * 32 + g4 * 8;
                const s16x8 a = *(const s16x8*)&vb[m16 * DIMK + (kel ^ ((m16 & 7) << 3))];
                const int slot = ((kk << 2) | g4) ^ (m16 & 7);
                const s16x8 b0 = *(const s16x8*)&buf[(wave * 32 + m16) * 64 + slot * 8];
                const s16x8 b1 = *(const s16x8*)&buf[(wave * 32 + 16 + m16) * 64 + slot * 8];
                h0 = __builtin_amdgcn_mfma_f32_16x16x32_bf16(a, b0, h0, 0, 0, 0);
                h1 = __builtin_amdgcn_mfma_f32_16x16x32_bf16(a, b1, h1, 0, 0, 0);
            }
            ++S;
        }
        // g = h*h -> gb  (visible to all by next step's B1+B2)
#pragma unroll
        for (int r = 0; r < 4; ++r) {
            const int m = g4 * 4 + r;
            gb[m * GPAD + n1a] = f2bf(h0[r] * h0[r]);
            gb[m * GPAD + n1b] = f2bf(h1[r] * h1[r]);
        }
        // ================= phase 2: Gamma = g @ W, chunks 16..31 ============
#pragma unroll
        for (int nt = 0; nt < 8; ++nt) acc[nt] = (f32x4){0.f, 0.f, 0.f, 0.f};
        for (int u = 0; u < 16; ++u) {
            asm volatile("s_waitcnt lgkmcnt(0)" ::: "memory");
            __builtin_amdgcn_s_barrier();                 // B1
            asm volatile("" ::: "memory");
            {
                const ushort_t* src = BC + ((S + 2) & 31) * CHUNK_US;
                ushort_t* dst = &ring[(S + 2) % 3][0];
#pragma unroll
                for (int i = 0; i < 4; ++i) {
                    const int q = i * 512 + tid;
                    gload_lds16(src + q * 8, dst + q * 8);
                }
            }
            asm volatile("s_waitcnt vmcnt(8)" ::: "memory");
            __builtin_amdgcn_s_barrier();                 // B2
            __builtin_amdgcn_sched_barrier(0);
            asm volatile("" ::: "memory");
            const ushort_t* buf = &ring[S % 3][0];
            if ((u & 1) == half_w) {                      // wave-uniform branch
                const int kel = (u >> 1) * 32 + g4 * 8;
                const s16x8 a = *(const s16x8*)&gb[m16 * GPAD + kel];
#pragma unroll
                for (int nt = 0; nt < 8; ++nt) {
                    const s16x8 b = *(const s16x8*)&buf[(wl * 128 + nt * 16 + m16) * 32 + g4 * 8];
                    acc[nt] = __builtin_amdgcn_mfma_f32_16x16x32_bf16(a, b, acc[nt], 0, 0, 0);
                }
            }
            ++S;
        }
        // ================= epilogue: v,x update + vb refresh ================
        const int ph = j - (j / 3) * 3;
        const float ddt = ((ph == 1) ? D2F : D1F) * DTF;
        const float cdt = ((ph == 2) ? ((j == n_acc - 1) ? C1F : THETAF) : C2F) * DTF;
#pragma unroll
        for (int nt = 0; nt < 8; ++nt) {
#pragma unroll
            for (int r = 0; r < 4; ++r) {
                const int i = nt * 4 + r;
                const int m = g4 * 4 + r;
                const int n = wave * 128 + nt * 16 + m16;
                const float vn = vreg[i] + ddt * (freg[i] - acc[nt][r]);
                vreg[i] = vn;
                xreg[i] += cdt * vn;
                vb[m * DIMK + (n ^ ((m & 7) << 3))] = f2bf(vn);
            }
        }
        // vb writes land before next step's B1 (lgkmcnt(0) precedes it)
    }

    // ---- write out: x then v, f32
    float* xo = out;
    float* vo = out + (size_t)BROWS * DIMK;
#pragma unroll
    for (int nt = 0; nt < 8; ++nt) {
#pragma unroll
        for (int r = 0; r < 4; ++r) {
            const int i = nt * 4 + r;
            const int m = g4 * 4 + r;
            const int n = wave * 128 + nt * 16 + m16;
            const size_t gi = (size_t)(row0 + m) * DIMK + n;
            xo[gi] = xreg[i];
            vo[gi] = vreg[i];
        }
    }
}

extern "C" void kernel_launch(void* const* d_in, const int* in_sizes, int n_in,
                              void* d_out, int out_size, void* d_ws, size_t ws_size,
                              hipStream_t stream) {
    const float* x = (const float*)d_in[0];
    const float* v = (const float*)d_in[1];
    const float* f = (const float*)d_in[2];
    const float* U = (const float*)d_in[3];   // [1024][256]
    const float* W = (const float*)d_in[4];   // [256][1024]
    const int* steps = (const int*)d_in[5];

    ushort_t* UtC = (ushort_t*)d_ws;                      // 16 chunks (512 KB)
    ushort_t* WtC = UtC + 16 * CHUNK_US;                  // 16 chunks (512 KB)
    float* out = (float*)d_out;

    fr_pack_u<<<1024, 256, 0, stream>>>(U, UtC);
    fr_pack_w<<<1024, 256, 0, stream>>>(W, WtC);
    fr_kernel<<<BROWS / TROWS, 512, 0, stream>>>(x, v, f, UtC, steps, out);
}